// Round 5
// baseline (442.783 us; speedup 1.0000x reference)
//
#include <hip/hip_runtime.h>

// SOM vector-quantizer for MI355X (gfx950).
// Outputs (flat in d_out): [0] loss scalar, [1 .. 8388608] quantized_st
// in [B,C,D,H,W] layout, [8388609 ..] one-hot encodings [N,256].
//
// N = 262144 voxels, EMB_D = 32, K = 256 (16x16 SOM grid).
//
// R4 -> R5: fused kernel was phase-serialization bound (~155us at <50% on
// every pipe; VPT=4 DS cut changed nothing). Split into two single-purpose
// kernels: (1) scan = pure-VALU argmin, writes BMU idx into enc row col0
// (scratch scribble, overwritten by (2)); (2) writer = pure streaming
// stores (one-hot + quantized) + loss partials. Each kernel runs near its
// own roofline instead of idling behind the other's latency.
// All distance math is R3-verbatim (bit-exact vs np reference, absmax 0.0).

#define SOM_K      256
#define EMB_D      32
#define WPAD       36             // LDS row stride (floats): 16B-aligned rows
#define N_VOX      262144
#define SPATIAL    32768          // 32*32*32 per batch
#define OUT_ELEMS  8388608        // 8*32*32768
#define COMMIT_DEN 8388608.0f
#define NSLOT      256            // loss accumulator slots (64B apart)

// ---------------------------------------------------------------------------
// prep: zero the slot accumulators (ws is poisoned to 0xAA every launch).
// Layout: ws[slot*16 + {0,1,2}] = {commit, som, count} partials.
// ---------------------------------------------------------------------------
__global__ __launch_bounds__(256) void som_prep_kernel(float* __restrict__ ws) {
  float4* p = (float4*)ws;               // 256 slots * 16 floats = 1024 float4
  int t = threadIdx.x;
#pragma unroll
  for (int i = 0; i < 4; ++i) p[i * 256 + t] = make_float4(0.f, 0.f, 0.f, 0.f);
}

// ---------------------------------------------------------------------------
// scan: 1024 blocks x 256 threads, one voxel per thread. Computes the BMU
// (argmin) index and stores it as an int into enc[n*256] (col 0 of this
// voxel's one-hot row — scratch space, fully overwritten by the writer).
// ---------------------------------------------------------------------------
__global__ __launch_bounds__(256) void som_scan_kernel(
    const float* __restrict__ x,     // [8,32,32,32,32]
    const float* __restrict__ w,     // [256,32]
    int* __restrict__ bidx_out) {    // (int*)enc, element stride SOM_K
  __shared__ __align__(16) float wl[SOM_K * WPAD];
  __shared__ float wsql[SOM_K];      // ||W_k||^2

  const int t = threadIdx.x;

  // Voxel loads first (overlap LDS staging). Coalesced per channel.
  const int n    = blockIdx.x * 256 + t;
  const int base = (n >> 15) * (EMB_D * SPATIAL) + (n & (SPATIAL - 1));
  float xv[EMB_D];
#pragma unroll
  for (int c = 0; c < EMB_D; ++c) xv[c] = x[base + c * SPATIAL];

  // Stage W -> LDS (coalesced read, padded scatter write).
#pragma unroll
  for (int i = 0; i < 32; ++i) {
    int e = i * 256 + t;             // 0..8191
    int r = e >> 5, c = e & 31;
    wl[r * WPAD + c] = w[e];
  }
  // ||W_t||^2, same sequential-fmaf order as the reference-matched R1-R3.
  {
    float s = 0.0f;
#pragma unroll
    for (int c = 0; c < EMB_D; ++c) {
      float v = w[t * EMB_D + c];
      s = fmaf(v, v, s);
    }
    wsql[t] = s;
  }
  __syncthreads();

  float xsq = 0.0f;
#pragma unroll
  for (int c = 0; c < EMB_D; ++c) xsq = fmaf(xv[c], xv[c], xsq);

  // Distance scan over all 256 rows via same-address float4 broadcast.
  // Exact sequential fmaf order (R1-R3: absmax 0.0); strict '<' = np.argmin.
  float best = 3.402823466e38f;
  int   bidx = 0;
#pragma unroll 2
  for (int k = 0; k < SOM_K; ++k) {
    const float4* row = (const float4*)(wl + k * WPAD);
    float dot = 0.0f;
#pragma unroll
    for (int j = 0; j < 8; ++j) {
      float4 q = row[j];
      dot = fmaf(q.x, xv[4 * j + 0], dot);
      dot = fmaf(q.y, xv[4 * j + 1], dot);
      dot = fmaf(q.z, xv[4 * j + 2], dot);
      dot = fmaf(q.w, xv[4 * j + 3], dot);
    }
    float d = (xsq + wsql[k]) - 2.0f * dot;   // same rounding order as ref
    if (d < best) { best = d; bidx = k; }
  }

  bidx_out[(size_t)n * SOM_K] = bidx;
}

// ---------------------------------------------------------------------------
// writer: 1024 blocks x 256 threads, one voxel per thread. Reads the BMU
// index back from enc col0 (each wave reads ONLY its own 64 rows, then
// overwrites them — every store's data depends on the loaded indices via
// v_readlane, so load-before-store ordering is guaranteed), then streams
// the one-hot rows + quantized output and accumulates the loss partials.
// ---------------------------------------------------------------------------
__global__ __launch_bounds__(256) void som_write_kernel(
    const float* __restrict__ x,     // [8,32,32,32,32]
    const float* __restrict__ w,     // [256,32]
    float* __restrict__ slots,       // ws: NSLOT x 16 floats
    float* __restrict__ out,         // d_out+1, [8,32,32768]
    float* enc) {                    // d_out+1+OUT_ELEMS, [N,256]
  __shared__ __align__(16) float wl[SOM_K * WPAD];
  __shared__ float wsql[SOM_K];      // ||W_k||^2

  const int t = threadIdx.x;
  const int n    = blockIdx.x * 256 + t;
  const int base = (n >> 15) * (EMB_D * SPATIAL) + (n & (SPATIAL - 1));

  // My voxel's BMU index (written by som_scan_kernel into my enc row col0).
  const int mybidx = ((const int*)enc)[(size_t)n * SOM_K];

  // Voxel vector (needed for commit/som losses).
  float xv[EMB_D];
#pragma unroll
  for (int c = 0; c < EMB_D; ++c) xv[c] = x[base + c * SPATIAL];

  // Stage W -> LDS + wsql (identical code to scan kernel -> identical fp).
#pragma unroll
  for (int i = 0; i < 32; ++i) {
    int e = i * 256 + t;
    int r = e >> 5, c = e & 31;
    wl[r * WPAD + c] = w[e];
  }
  {
    float s = 0.0f;
#pragma unroll
    for (int c = 0; c < EMB_D; ++c) {
      float v = w[t * EMB_D + c];
      s = fmaf(v, v, s);
    }
    wsql[t] = s;
  }
  __syncthreads();

  float xsq = 0.0f;
#pragma unroll
  for (int c = 0; c < EMB_D; ++c) xsq = fmaf(xv[c], xv[c], xsq);

  // One-hot encodings: wave broadcasts its own 64 row indices via v_readlane
  // (lane r of wave w holds row b*256+w*64+r's index == its own mybidx).
  // Coalesced 256B dword stores (enc starts at float offset 1 mod 4).
  {
    const int lane = t & 63, wave = t >> 6;
    float* ep = enc + (size_t)(blockIdx.x * 256 + wave * 64) * SOM_K + lane;
    const int c1 = lane + 64, c2 = lane + 128, c3 = lane + 192;
    for (int row = 0; row < 64; ++row) {
      const int src = __builtin_amdgcn_readlane(mybidx, row);  // wave-uniform
      ep[0]   = (lane == src) ? 1.0f : 0.0f;
      ep[64]  = (c1   == src) ? 1.0f : 0.0f;
      ep[128] = (c2   == src) ? 1.0f : 0.0f;
      ep[192] = (c3   == src) ? 1.0f : 0.0f;
      ep += SOM_K;
    }
  }

  // Quantized output + commitment partial (gather row mybidx from LDS).
  float commit = 0.0f;
  {
    const float4* qrow = (const float4*)(wl + mybidx * WPAD);
#pragma unroll
    for (int j = 0; j < 8; ++j) {
      float4 q = qrow[j];
      float qq[4] = { q.x, q.y, q.z, q.w };
#pragma unroll
      for (int u = 0; u < 4; ++u) {
        int c = 4 * j + u;
        out[base + c * SPATIAL] = qq[u];     // coalesced dword store
        float df = qq[u] - xv[c];
        commit = fmaf(df, df, commit);
      }
    }
  }

  // SOM loss: recompute BMU distance (identical fp sequence to the scan ->
  // bit-identical value) + up/down/left/right neighbors.
  float som, cnt = 1.0f;
  {
    const float4* brow = (const float4*)(wl + mybidx * WPAD);
    float dot = 0.0f;
#pragma unroll
    for (int j = 0; j < 8; ++j) {
      float4 q = brow[j];
      dot = fmaf(q.x, xv[4 * j + 0], dot);
      dot = fmaf(q.y, xv[4 * j + 1], dot);
      dot = fmaf(q.z, xv[4 * j + 2], dot);
      dot = fmaf(q.w, xv[4 * j + 3], dot);
    }
    som = (xsq + wsql[mybidx]) - 2.0f * dot;
  }
  {
    const int h  = mybidx >> 4;
    const int wc = mybidx & 15;
    const int   cand[4]  = { mybidx - 16, mybidx + 16, mybidx - 1, mybidx + 1 };
    const float valid[4] = { h > 0 ? 1.f : 0.f,  h < 15 ? 1.f : 0.f,
                             wc > 0 ? 1.f : 0.f, wc < 15 ? 1.f : 0.f };
#pragma unroll
    for (int j = 0; j < 4; ++j) {
      int nk = valid[j] != 0.0f ? cand[j] : mybidx;
      const float4* nrow = (const float4*)(wl + nk * WPAD);
      float dot = 0.0f;
#pragma unroll
      for (int jj = 0; jj < 8; ++jj) {
        float4 q = nrow[jj];
        dot = fmaf(q.x, xv[4 * jj + 0], dot);
        dot = fmaf(q.y, xv[4 * jj + 1], dot);
        dot = fmaf(q.z, xv[4 * jj + 2], dot);
        dot = fmaf(q.w, xv[4 * jj + 3], dot);
      }
      float d = (xsq + wsql[nk]) - 2.0f * dot;
      som = fmaf(valid[j], d, som);
      cnt += valid[j];
    }
  }

  // Wave reduction -> 3 atomics per wave into this block's slot (slots 64B
  // apart; 4 waves/slot -> negligible contention).
  for (int off = 32; off > 0; off >>= 1) {
    commit += __shfl_down(commit, off, 64);
    som    += __shfl_down(som,    off, 64);
    cnt    += __shfl_down(cnt,    off, 64);
  }
  if ((t & 63) == 0) {
    float* sp = slots + (size_t)(blockIdx.x & (NSLOT - 1)) * 16;
    atomicAdd(sp + 0, commit);
    atomicAdd(sp + 1, som);
    atomicAdd(sp + 2, cnt);
  }
}

// ---------------------------------------------------------------------------
// final: reduce the 256 slots with one wave, then
// loss = ALPHA * mean(commit) + BETA * som_sum / total_neighbors
// ---------------------------------------------------------------------------
__global__ __launch_bounds__(64) void som_final_kernel(
    const float* __restrict__ slots, float* __restrict__ loss) {
  const int t = threadIdx.x;           // one wave
  float commit = 0.f, som = 0.f, cnt = 0.f;
#pragma unroll
  for (int i = 0; i < 4; ++i) {
    const float* sp = slots + (size_t)(i * 64 + t) * 16;
    commit += sp[0]; som += sp[1]; cnt += sp[2];
  }
  for (int off = 32; off > 0; off >>= 1) {
    commit += __shfl_down(commit, off, 64);
    som    += __shfl_down(som,    off, 64);
    cnt    += __shfl_down(cnt,    off, 64);
  }
  if (t == 0) loss[0] = 6.0f * (commit / COMMIT_DEN) + som / cnt;
}

extern "C" void kernel_launch(void* const* d_in, const int* in_sizes, int n_in,
                              void* d_out, int out_size, void* d_ws, size_t ws_size,
                              hipStream_t stream) {
  const float* x = (const float*)d_in[0];   // [8,32,32,32,32]
  const float* w = (const float*)d_in[1];   // [256,32]
  float* ws  = (float*)d_ws;                // NSLOT x 16 float slots
  float* o   = (float*)d_out;               // [0] loss, then out, then enc
  float* enc = o + 1 + OUT_ELEMS;

  som_prep_kernel<<<1, 256, 0, stream>>>(ws);
  som_scan_kernel<<<N_VOX / 256, 256, 0, stream>>>(x, w, (int*)enc);
  som_write_kernel<<<N_VOX / 256, 256, 0, stream>>>(x, w, ws, o + 1, enc);
  som_final_kernel<<<1, 64, 0, stream>>>(ws, o);
}